// Round 3
// baseline (203.313 us; speedup 1.0000x reference)
//
#include <hip/hip_runtime.h>
#include <hip/hip_bf16.h>
#include <stdint.h>

#define B_  2
#define S_  2048
#define D_  1024
#define H_  16
#define DH_ 64

typedef __attribute__((ext_vector_type(8))) __bf16    bf16x8;
typedef __attribute__((ext_vector_type(8))) _Float16  f16x8;
typedef __attribute__((ext_vector_type(4))) _Float16  f16x4;
typedef __attribute__((ext_vector_type(2))) __fp16    fp16x2;   // cvt_pkrtz return type
typedef __attribute__((ext_vector_type(4))) float     f32x4;

__device__ inline unsigned short f2bf(float f) {
    union { float f; uint32_t u; } v; v.f = f;
    uint32_t r = (v.u + 0x7fffu + ((v.u >> 16) & 1u)) >> 16;
    return (unsigned short)r;
}

// async global->LDS, 16B per lane. LDS dest = wave-uniform base + lane*16.
__device__ __forceinline__ void g2l16(const unsigned short* g, unsigned short* l) {
    __builtin_amdgcn_global_load_lds(
        (const __attribute__((address_space(1))) unsigned int*)g,
        (__attribute__((address_space(3))) unsigned int*)l,
        16, 0, 0);
}

// ---------------- conversion kernels ----------------

__global__ void convert_x(const float* __restrict__ x, unsigned short* __restrict__ xb, int n) {
    int i = (blockIdx.x * blockDim.x + threadIdx.x) * 4;
    if (i < n) {
        float4 v = *(const float4*)(x + i);
        ushort4 o;
        o.x = f2bf(v.x); o.y = f2bf(v.y); o.z = f2bf(v.z); o.w = f2bf(v.w);
        *(ushort4*)(xb + i) = o;
    }
}

// transpose+convert 1024x1024 fp32 [K][N] -> bf16 [N][K]; z selects matrix
__global__ void transpose_w(const float* __restrict__ s0, const float* __restrict__ s1,
                            const float* __restrict__ s2, const float* __restrict__ s3,
                            unsigned short* __restrict__ d0, unsigned short* __restrict__ d1,
                            unsigned short* __restrict__ d2, unsigned short* __restrict__ d3) {
    __shared__ float tile[32][33];
    const float* src; unsigned short* dst;
    switch (blockIdx.z) {
        case 0: src = s0; dst = d0; break;
        case 1: src = s1; dst = d1; break;
        case 2: src = s2; dst = d2; break;
        default: src = s3; dst = d3; break;
    }
    int n0 = blockIdx.x * 32, k0 = blockIdx.y * 32;
    int tx = threadIdx.x, ty = threadIdx.y;   // (32, 8)
    for (int j = 0; j < 32; j += 8)
        tile[ty + j][tx] = src[(long)(k0 + ty + j) * 1024 + n0 + tx];
    __syncthreads();
    for (int j = 0; j < 32; j += 8)
        dst[(long)(n0 + ty + j) * 1024 + k0 + tx] = f2bf(tile[tx][ty + j]);
}

// ---------------- 128x128 MFMA GEMM, global_load_lds staging ----------------
// MODE 0: scatter epilogue -> Q[B,H,S,64] bf16 (PRE-SCALED by 0.125*log2e),
//         K[B,H,S,64] bf16 (PRE-SCALED by fw[s] - fractal weight folded in),
//         Vt[B,H,64,S] FP16
// MODE 1: C fp32 [M,1024] row-major
template<int MODE>
__global__ __launch_bounds__(256, 2)
void gemm128(const unsigned short* __restrict__ A, const unsigned short* __restrict__ Bt,
             unsigned short* __restrict__ Qo, unsigned short* __restrict__ Ko,
             unsigned short* __restrict__ Vt, float* __restrict__ Cout,
             const float* __restrict__ fw)
{
    __shared__ __align__(16) unsigned short As[128 * 64];
    __shared__ __align__(16) unsigned short Bs[128 * 64];
    const int tid  = threadIdx.x;
    const int lane = tid & 63, wid = tid >> 6;
    const int quad = lane >> 4, l15 = lane & 15;
    const int wm = wid >> 1, wn = wid & 1;
    const int bm = blockIdx.y, bn = blockIdx.x;
    const int K = 1024;
    f32x4 acc[4][4] = {};
    const long Abase = (long)bm * 128 * K;
    const long Bbase = (long)bn * 128 * K;

    for (int k0 = 0; k0 < K; k0 += 64) {
        __syncthreads();
#pragma unroll
        for (int i = 0; i < 4; i++) {
            int slot = i * 256 + wid * 64 + lane;
            int row = slot >> 3, cp = slot & 7;
            int c = cp ^ (row & 7);
            g2l16(A + Abase + (long)row * K + k0 + c * 8, &As[(i * 256 + wid * 64) * 8]);
        }
#pragma unroll
        for (int i = 0; i < 4; i++) {
            int slot = i * 256 + wid * 64 + lane;
            int row = slot >> 3, cp = slot & 7;
            int c = cp ^ (row & 7);
            g2l16(Bt + Bbase + (long)row * K + k0 + c * 8, &Bs[(i * 256 + wid * 64) * 8]);
        }
        __syncthreads();
#pragma unroll
        for (int ks = 0; ks < 2; ks++) {
            bf16x8 af[4], bfr[4];
#pragma unroll
            for (int t = 0; t < 4; t++) {
                int ra = wm * 64 + t * 16 + l15;
                af[t]  = *(const bf16x8*)(As + ra * 64 + (((ks * 4 + quad) ^ (l15 & 7))) * 8);
                int rb = wn * 64 + t * 16 + l15;
                bfr[t] = *(const bf16x8*)(Bs + rb * 64 + (((ks * 4 + quad) ^ (l15 & 7))) * 8);
            }
#pragma unroll
            for (int tm = 0; tm < 4; tm++)
#pragma unroll
                for (int tn = 0; tn < 4; tn++)
                    acc[tm][tn] = __builtin_amdgcn_mfma_f32_16x16x32_bf16(af[tm], bfr[tn], acc[tm][tn], 0, 0, 0);
        }
    }

    const float Cq = 0.125f * 1.44269504f;   // score scale * log2(e), folded into Q
    for (int tm = 0; tm < 4; tm++)
        for (int tn = 0; tn < 4; tn++)
            for (int r = 0; r < 4; r++) {
                int gm = bm * 128 + wm * 64 + tm * 16 + quad * 4 + r;
                int gn = bn * 128 + wn * 64 + tn * 16 + l15;
                float v = acc[tm][tn][r];
                if (MODE == 0) {
                    int b = gm >> 11, s = gm & 2047;
                    if (gn < 1024) {
                        int h = gn >> 6, d = gn & 63;
                        Qo[(((long)(b * H_ + h) * S_ + s) << 6) + d] = f2bf(v * Cq);
                    } else if (gn < 2048) {
                        int g = gn - 1024; int h = g >> 6, d = g & 63;
                        Ko[(((long)(b * H_ + h) * S_ + s) << 6) + d] = f2bf(v * fw[s]);
                    } else {
                        int g = gn - 2048; int h = g >> 6, d = g & 63;
                        union { _Float16 h; unsigned short u; } cv;
                        cv.h = (_Float16)v;                       // V^T stored FP16
                        Vt[((long)(b * H_ + h) * DH_ + d) * S_ + s] = cv.u;
                    }
                } else {
                    Cout[(long)gm * 1024 + gn] = v;
                }
            }
}

// ---------------- flash attention ----------------
// R12: occupancy fix. R11 counters: Occupancy 18.6%, MfmaUtil 20, VALUBusy 35,
// HBM 14.7% - NOTHING saturated; grid (32,32)x2waves = exactly 8 waves/CU
// (25% cap) was the limiter (LDS 32KB and VGPR 88 both allow more).
// Fix: QBLK 64->128, 4 waves/block (each wave keeps 32 q-rows = 2 strips
// sharing V-fragments, so LDS read traffic per unit work is UNCHANGED -
// a 16-qrow/wave split would double LDS reads and wall at ~100% LDS).
// Grid (16,32) = 512 blocks = 2 blocks/CU x 4 waves = 16 waves/CU (4/SIMD).
// K/V re-fetch per head halves too (16 q-blocks instead of 32).
// Register-P (R8): S^T = mfma(K_frag, Q_frag) -> acc[key=quad*4+r][q=l15];
// exp2 packed via cvt_pkrtz IS the PV A-fragment; P never touches LDS.
// fw folded into K at gemm0, Q pre-scaled by 0.125*log2e -> softmax is
// literally exp2(sacc). Max-free: fractal weights sum to 1 => |arg| < ~0.1.
// R10: PV K=32 f16 mfma; key-order is a free bijection, [sacc[2c]|sacc[2c+1]]
// packed to f16x8 IS a valid A-fragment; B-frag = concat of the two swizzled
// f16x4 V^T chunks at the matching addresses.
__global__ __launch_bounds__(256, 4)
void attn_kernel(const unsigned short* __restrict__ Q, const unsigned short* __restrict__ Kb,
                 const unsigned short* __restrict__ Vt,
                 unsigned short* __restrict__ O)
{
    __shared__ __align__(16) unsigned short Ks[2][64 * 64];
    __shared__ __align__(16) unsigned short Vs[2][64 * 64];

    const int tid  = threadIdx.x;
    const int lane = tid & 63, wid = tid >> 6;    // wid in {0..3}
    const int quad = lane >> 4, l15 = lane & 15;
    const int bh = blockIdx.y;
    const int qt = blockIdx.x;                    // 128 q-rows per block

    const unsigned short* Kg = Kb + (long)bh * S_ * DH_;
    const unsigned short* Vg = Vt + (long)bh * (long)DH_ * S_;

    bf16x8 qf[2][2];
#pragma unroll
    for (int s = 0; s < 2; s++) {
        const unsigned short* Qp = Q + ((long)bh * S_ + qt * 128 + wid * 32 + s * 16 + l15) * DH_ + quad * 8;
        qf[s][0] = *(const bf16x8*)(Qp);
        qf[s][1] = *(const bf16x8*)(Qp + 32);
    }

    // stage tile kt: 512 16B-chunks each for K and V, 4 waves x 2 issues each
    auto issue = [&](int buf, int kt) {
#pragma unroll
        for (int i = 0; i < 2; i++) {
            int base = i * 256 + wid * 64;
            int slot = base + lane;
            int row = slot >> 3, cp = slot & 7;
            int c = cp ^ (row & 7);
            g2l16(Kg + ((long)(kt * 64 + row) * 64 + c * 8), &Ks[buf][base * 8]);
        }
#pragma unroll
        for (int i = 0; i < 2; i++) {
            int base = i * 256 + wid * 64;
            int slot = base + lane;
            int row = slot >> 3, cp = slot & 7;
            int c = cp ^ (row & 7);
            g2l16(Vg + ((long)row * S_ + kt * 64 + c * 8), &Vs[buf][base * 8]);
        }
    };

    f32x4 oacc[2][4] = {};
    float l_r[2] = {0.f, 0.f};

    issue(0, 0);
    __syncthreads();

    for (int kt = 0; kt < S_ / 64; kt++) {
        const int cur = kt & 1;
        if (kt + 1 < S_ / 64) issue(1 - cur, kt + 1);

        const unsigned short* Kc = &Ks[cur][0];
        const unsigned short* Vc = &Vs[cur][0];

        // ---- S^T tiles: mfma(K_frag, Q_frag) -> [key=quad*4+r][q=l15] ----
        f32x4 sacc[2][4] = {};
#pragma unroll
        for (int kc = 0; kc < 4; kc++) {
            int row = kc * 16 + l15;
            bf16x8 k0 = *(const bf16x8*)(Kc + (row * 8 + (quad       ^ (l15 & 7))) * 8);
            bf16x8 k1 = *(const bf16x8*)(Kc + (row * 8 + ((4 + quad) ^ (l15 & 7))) * 8);
#pragma unroll
            for (int s = 0; s < 2; s++) {
                sacc[s][kc] = __builtin_amdgcn_mfma_f32_16x16x32_bf16(k0, qf[s][0], sacc[s][kc], 0, 0, 0);
                sacc[s][kc] = __builtin_amdgcn_mfma_f32_16x16x32_bf16(k1, qf[s][1], sacc[s][kc], 0, 0, 0);
            }
        }

        // ---- p = 2^sacc packed straight into K=32 f16 PV A-fragments ----
        // pk8[s][c] halves [h*4+r] = exp2(sacc[s][2c+h][r]); lane k-slice
        // quad*8+i maps to keys c*32 + h*16 + quad*4 + r (see header note).
        f16x8 pk8[2][2];
#pragma unroll
        for (int s = 0; s < 2; s++)
#pragma unroll
            for (int c = 0; c < 2; c++) {
                union { uint4 u; f16x8 v; } pku;
#pragma unroll
                for (int h = 0; h < 2; h++) {
                    float p0 = __builtin_amdgcn_exp2f(sacc[s][2 * c + h][0]);
                    float p1 = __builtin_amdgcn_exp2f(sacc[s][2 * c + h][1]);
                    float p2 = __builtin_amdgcn_exp2f(sacc[s][2 * c + h][2]);
                    float p3 = __builtin_amdgcn_exp2f(sacc[s][2 * c + h][3]);
                    l_r[s] += (p0 + p1) + (p2 + p3);
                    union { fp16x2 h2; unsigned int u; } a, b;
                    a.h2 = __builtin_amdgcn_cvt_pkrtz(p0, p1);
                    b.h2 = __builtin_amdgcn_cvt_pkrtz(p2, p3);
                    if (h == 0) { pku.u.x = a.u; pku.u.y = b.u; }
                    else        { pku.u.z = a.u; pku.u.w = b.u; }
                }
                pk8[s][c] = pku.v;
            }

        // ---- O += P V via K=32 f16 mfma; B-frag = concat of two swizzled
        //      f16x4 V^T chunks; vf8 shared by both q-strips ----
#pragma unroll
        for (int c = 0; c < 2; c++)
#pragma unroll
            for (int dt = 0; dt < 4; dt++) {
                int row = dt * 16 + l15;
                int p0 = (c * 4 +     (quad >> 1)) ^ (l15 & 7);   // keys c*32+quad*4..+3
                int p1 = (c * 4 + 2 + (quad >> 1)) ^ (l15 & 7);   // keys c*32+16+quad*4..+3
                f16x4 v0 = *(const f16x4*)(Vc + row * 64 + p0 * 8 + (quad & 1) * 4);
                f16x4 v1 = *(const f16x4*)(Vc + row * 64 + p1 * 8 + (quad & 1) * 4);
                f16x8 vf8 = __builtin_shufflevector(v0, v1, 0, 1, 2, 3, 4, 5, 6, 7);
                oacc[0][dt] = __builtin_amdgcn_mfma_f32_16x16x32_f16(pk8[0][c], vf8, oacc[0][dt], 0, 0, 0);
                oacc[1][dt] = __builtin_amdgcn_mfma_f32_16x16x32_f16(pk8[1][c], vf8, oacc[1][dt], 0, 0, 0);
            }

        __syncthreads();
    }

    // l reduction: sum over quads (keys were split across quad+regs)
#pragma unroll
    for (int s = 0; s < 2; s++) {
        l_r[s] += __shfl_xor(l_r[s], 16);
        l_r[s] += __shfl_xor(l_r[s], 32);
    }

    int b = bh >> 4, h = bh & 15;
#pragma unroll
    for (int s = 0; s < 2; s++)
#pragma unroll
        for (int r = 0; r < 4; r++) {
            float inv = 1.0f / __shfl(l_r[s], quad * 4 + r);   // lane q4r holds qrow q4r's sum
            int srow = qt * 128 + wid * 32 + s * 16 + quad * 4 + r;
#pragma unroll
            for (int dt = 0; dt < 4; dt++)
                O[((long)(b * S_ + srow)) * 1024 + h * DH_ + dt * 16 + l15] = f2bf(oacc[s][dt][r] * inv);
        }
}

// ---------------- launch ----------------

extern "C" void kernel_launch(void* const* d_in, const int* in_sizes, int n_in,
                              void* d_out, int out_size, void* d_ws, size_t ws_size,
                              hipStream_t stream)
{
    const float* x  = (const float*)d_in[0];
    const float* Wq = (const float*)d_in[1];
    const float* Wk = (const float*)d_in[2];
    const float* Wv = (const float*)d_in[3];
    const float* Wo = (const float*)d_in[4];
    const float* fw = (const float*)d_in[5];
    float* out = (float*)d_out;

    char* ws = (char*)d_ws;
    unsigned short* xb    = (unsigned short*)(ws);               // 8 MB   [B*S, D] bf16
    unsigned short* WqkvT = (unsigned short*)(ws + 8388608);     // 6 MB   [3072,1024] bf16
    unsigned short* WoT   = (unsigned short*)(ws + 14680064);    // 2 MB   [1024,1024] bf16
    unsigned short* Qb    = (unsigned short*)(ws + 16777216);    // 8 MB   [B,H,S,64] bf16 (pre-scaled Cq)
    unsigned short* Kb    = (unsigned short*)(ws + 25165824);    // 8 MB   [B,H,S,64] bf16 (pre-scaled fw)
    unsigned short* Vt    = (unsigned short*)(ws + 33554432);    // 8 MB   [B,H,64,S] fp16
    unsigned short* Ob    = xb;                                  // alias: xb dead after gemm1

    convert_x<<<dim3((B_ * S_ * D_) / 4 / 256), dim3(256), 0, stream>>>(x, xb, B_ * S_ * D_);
    transpose_w<<<dim3(32, 32, 4), dim3(32, 8), 0, stream>>>(
        Wq, Wk, Wv, Wo,
        WqkvT, WqkvT + 1024 * 1024, WqkvT + 2 * 1024 * 1024, WoT);
    gemm128<0><<<dim3(24, 32), dim3(256), 0, stream>>>(xb, WqkvT, Qb, Kb, Vt, (float*)nullptr, fw);
    attn_kernel<<<dim3(S_ / 128, B_ * H_), dim3(256), 0, stream>>>(Qb, Kb, Vt, Ob);
    gemm128<1><<<dim3(8, 32), dim3(256), 0, stream>>>(Ob, WoT,
        (unsigned short*)nullptr, (unsigned short*)nullptr, (unsigned short*)nullptr, out, (const float*)nullptr);
}

// Round 4
// 193.431 us; speedup vs baseline: 1.0511x; 1.0511x over previous
//
#include <hip/hip_runtime.h>
#include <hip/hip_bf16.h>
#include <stdint.h>

#define B_  2
#define S_  2048
#define D_  1024
#define H_  16
#define DH_ 64

typedef __attribute__((ext_vector_type(8))) __bf16    bf16x8;
typedef __attribute__((ext_vector_type(8))) _Float16  f16x8;
typedef __attribute__((ext_vector_type(4))) _Float16  f16x4;
typedef __attribute__((ext_vector_type(2))) __fp16    fp16x2;   // cvt_pkrtz return type
typedef __attribute__((ext_vector_type(4))) float     f32x4;

__device__ inline unsigned short f2bf(float f) {
    union { float f; uint32_t u; } v; v.f = f;
    uint32_t r = (v.u + 0x7fffu + ((v.u >> 16) & 1u)) >> 16;
    return (unsigned short)r;
}

// async global->LDS, 16B per lane. LDS dest = wave-uniform base + lane*16.
__device__ __forceinline__ void g2l16(const unsigned short* g, unsigned short* l) {
    __builtin_amdgcn_global_load_lds(
        (const __attribute__((address_space(1))) unsigned int*)g,
        (__attribute__((address_space(3))) unsigned int*)l,
        16, 0, 0);
}

// ---------------- conversion kernels ----------------

__global__ void convert_x(const float* __restrict__ x, unsigned short* __restrict__ xb, int n) {
    int i = (blockIdx.x * blockDim.x + threadIdx.x) * 4;
    if (i < n) {
        float4 v = *(const float4*)(x + i);
        ushort4 o;
        o.x = f2bf(v.x); o.y = f2bf(v.y); o.z = f2bf(v.z); o.w = f2bf(v.w);
        *(ushort4*)(xb + i) = o;
    }
}

// transpose+convert 1024x1024 fp32 [K][N] -> bf16 [N][K]; z selects matrix
__global__ void transpose_w(const float* __restrict__ s0, const float* __restrict__ s1,
                            const float* __restrict__ s2, const float* __restrict__ s3,
                            unsigned short* __restrict__ d0, unsigned short* __restrict__ d1,
                            unsigned short* __restrict__ d2, unsigned short* __restrict__ d3) {
    __shared__ float tile[32][33];
    const float* src; unsigned short* dst;
    switch (blockIdx.z) {
        case 0: src = s0; dst = d0; break;
        case 1: src = s1; dst = d1; break;
        case 2: src = s2; dst = d2; break;
        default: src = s3; dst = d3; break;
    }
    int n0 = blockIdx.x * 32, k0 = blockIdx.y * 32;
    int tx = threadIdx.x, ty = threadIdx.y;   // (32, 8)
    for (int j = 0; j < 32; j += 8)
        tile[ty + j][tx] = src[(long)(k0 + ty + j) * 1024 + n0 + tx];
    __syncthreads();
    for (int j = 0; j < 32; j += 8)
        dst[(long)(n0 + ty + j) * 1024 + k0 + tx] = f2bf(tile[tx][ty + j]);
}

// ---------------- 128x128 MFMA GEMM, global_load_lds staging ----------------
// MODE 0: scatter epilogue -> Q[B,H,S,64] bf16 (PRE-SCALED by 0.125*log2e),
//         K[B,H,S,64] bf16 (PRE-SCALED by fw[s] - fractal weight folded in),
//         Vt[B,H,64,S] FP16, with per-row half-swap: column s stored at
//         s ^ ((d&8)?4:0). R13: this is the source side of the attn V-read
//         bank-conflict fix (LDS half bit XORed with row>>3 on read).
// MODE 1: C fp32 [M,1024] row-major
template<int MODE>
__global__ __launch_bounds__(256, 2)
void gemm128(const unsigned short* __restrict__ A, const unsigned short* __restrict__ Bt,
             unsigned short* __restrict__ Qo, unsigned short* __restrict__ Ko,
             unsigned short* __restrict__ Vt, float* __restrict__ Cout,
             const float* __restrict__ fw)
{
    __shared__ __align__(16) unsigned short As[128 * 64];
    __shared__ __align__(16) unsigned short Bs[128 * 64];
    const int tid  = threadIdx.x;
    const int lane = tid & 63, wid = tid >> 6;
    const int quad = lane >> 4, l15 = lane & 15;
    const int wm = wid >> 1, wn = wid & 1;
    const int bm = blockIdx.y, bn = blockIdx.x;
    const int K = 1024;
    f32x4 acc[4][4] = {};
    const long Abase = (long)bm * 128 * K;
    const long Bbase = (long)bn * 128 * K;

    for (int k0 = 0; k0 < K; k0 += 64) {
        __syncthreads();
#pragma unroll
        for (int i = 0; i < 4; i++) {
            int slot = i * 256 + wid * 64 + lane;
            int row = slot >> 3, cp = slot & 7;
            int c = cp ^ (row & 7);
            g2l16(A + Abase + (long)row * K + k0 + c * 8, &As[(i * 256 + wid * 64) * 8]);
        }
#pragma unroll
        for (int i = 0; i < 4; i++) {
            int slot = i * 256 + wid * 64 + lane;
            int row = slot >> 3, cp = slot & 7;
            int c = cp ^ (row & 7);
            g2l16(Bt + Bbase + (long)row * K + k0 + c * 8, &Bs[(i * 256 + wid * 64) * 8]);
        }
        __syncthreads();
#pragma unroll
        for (int ks = 0; ks < 2; ks++) {
            bf16x8 af[4], bfr[4];
#pragma unroll
            for (int t = 0; t < 4; t++) {
                int ra = wm * 64 + t * 16 + l15;
                af[t]  = *(const bf16x8*)(As + ra * 64 + (((ks * 4 + quad) ^ (l15 & 7))) * 8);
                int rb = wn * 64 + t * 16 + l15;
                bfr[t] = *(const bf16x8*)(Bs + rb * 64 + (((ks * 4 + quad) ^ (l15 & 7))) * 8);
            }
#pragma unroll
            for (int tm = 0; tm < 4; tm++)
#pragma unroll
                for (int tn = 0; tn < 4; tn++)
                    acc[tm][tn] = __builtin_amdgcn_mfma_f32_16x16x32_bf16(af[tm], bfr[tn], acc[tm][tn], 0, 0, 0);
        }
    }

    const float Cq = 0.125f * 1.44269504f;   // score scale * log2(e), folded into Q
    for (int tm = 0; tm < 4; tm++)
        for (int tn = 0; tn < 4; tn++)
            for (int r = 0; r < 4; r++) {
                int gm = bm * 128 + wm * 64 + tm * 16 + quad * 4 + r;
                int gn = bn * 128 + wn * 64 + tn * 16 + l15;
                float v = acc[tm][tn][r];
                if (MODE == 0) {
                    int b = gm >> 11, s = gm & 2047;
                    if (gn < 1024) {
                        int h = gn >> 6, d = gn & 63;
                        Qo[(((long)(b * H_ + h) * S_ + s) << 6) + d] = f2bf(v * Cq);
                    } else if (gn < 2048) {
                        int g = gn - 1024; int h = g >> 6, d = g & 63;
                        Ko[(((long)(b * H_ + h) * S_ + s) << 6) + d] = f2bf(v * fw[s]);
                    } else {
                        int g = gn - 2048; int h = g >> 6, d = g & 63;
                        union { _Float16 h; unsigned short u; } cv;
                        cv.h = (_Float16)v;                       // V^T stored FP16
                        int sp = s ^ ((d & 8) ? 4 : 0);           // R13 half-swap involution
                        Vt[((long)(b * H_ + h) * DH_ + d) * S_ + sp] = cv.u;
                    }
                } else {
                    Cout[(long)gm * 1024 + gn] = v;
                }
            }
}

// ---------------- flash attention ----------------
// R13: TWO measured fixes.
// (a) Occupancy: total waves = q-rows/q-rows-per-wave. At 32 q-rows/wave the
//     machine caps at 8 waves/CU regardless of block shape (R12 lesson).
//     Now 16 q-rows/wave -> 4096 waves = 16 waves/CU (4/SIMD), QBLK=64,
//     4 waves/block, grid (32,32) = 1024 blocks = 4 barrier domains/CU.
// (b) V-read bank conflicts (SQ_LDS_BANK_CONFLICT 4.19M = 64 cy/wave-kt):
//     b64 V reads had bank = chunk*4+half*2 (row*128B wraps mod banks) ->
//     16 start banks for 64 lanes = 2x serialization. Fix: half bit XOR
//     (l15>>3), matched by the global-side involution in gemm0's V write
//     (both-sides-or-neither). Banks now cover all 32 -> BW-minimum 4 clk.
// Register-P (R8): S^T = mfma(K_frag, Q_frag) -> acc[key=quad*4+r][q=l15];
// exp2 packed via cvt_pkrtz IS the PV A-fragment; P never touches LDS.
// fw folded into K at gemm0, Q pre-scaled by 0.125*log2e -> softmax is
// literally exp2(sacc). Max-free: fractal weights sum to 1 => |arg| < ~0.1.
// R10: PV K=32 f16 mfma; key-order is a free bijection, [sacc[2c]|sacc[2c+1]]
// packed to f16x8 IS a valid A-fragment; B-frag = concat of the two swizzled
// f16x4 V^T chunks at the matching addresses.
__global__ __launch_bounds__(256, 4)
void attn_kernel(const unsigned short* __restrict__ Q, const unsigned short* __restrict__ Kb,
                 const unsigned short* __restrict__ Vt,
                 unsigned short* __restrict__ O)
{
    __shared__ __align__(16) unsigned short Ks[2][64 * 64];
    __shared__ __align__(16) unsigned short Vs[2][64 * 64];

    const int tid  = threadIdx.x;
    const int lane = tid & 63, wid = tid >> 6;    // wid in {0..3}
    const int quad = lane >> 4, l15 = lane & 15;
    const int bh = blockIdx.y;
    const int qt = blockIdx.x;                    // 64 q-rows per block, 16 per wave

    const unsigned short* Kg = Kb + (long)bh * S_ * DH_;
    const unsigned short* Vg = Vt + (long)bh * (long)DH_ * S_;

    bf16x8 qf[2];
    {
        const unsigned short* Qp = Q + ((long)bh * S_ + qt * 64 + wid * 16 + l15) * DH_ + quad * 8;
        qf[0] = *(const bf16x8*)(Qp);
        qf[1] = *(const bf16x8*)(Qp + 32);
    }

    // stage tile kt: 512 16B-chunks each for K and V, 4 waves x 2 issues each
    auto issue = [&](int buf, int kt) {
#pragma unroll
        for (int i = 0; i < 2; i++) {
            int base = i * 256 + wid * 64;
            int slot = base + lane;
            int row = slot >> 3, cp = slot & 7;
            int c = cp ^ (row & 7);
            g2l16(Kg + ((long)(kt * 64 + row) * 64 + c * 8), &Ks[buf][base * 8]);
        }
#pragma unroll
        for (int i = 0; i < 2; i++) {
            int base = i * 256 + wid * 64;
            int slot = base + lane;
            int row = slot >> 3, cp = slot & 7;
            int c = cp ^ (row & 7);
            g2l16(Vg + ((long)row * S_ + kt * 64 + c * 8), &Vs[buf][base * 8]);
        }
    };

    f32x4 oacc[4] = {};
    float l_r = 0.f;

    issue(0, 0);
    __syncthreads();

    for (int kt = 0; kt < S_ / 64; kt++) {
        const int cur = kt & 1;
        if (kt + 1 < S_ / 64) issue(1 - cur, kt + 1);

        const unsigned short* Kc = &Ks[cur][0];
        const unsigned short* Vc = &Vs[cur][0];

        // ---- S^T tiles: mfma(K_frag, Q_frag) -> [key=quad*4+r][q=l15] ----
        f32x4 sacc[4] = {};
#pragma unroll
        for (int kc = 0; kc < 4; kc++) {
            int row = kc * 16 + l15;
            bf16x8 k0 = *(const bf16x8*)(Kc + (row * 8 + (quad       ^ (l15 & 7))) * 8);
            bf16x8 k1 = *(const bf16x8*)(Kc + (row * 8 + ((4 + quad) ^ (l15 & 7))) * 8);
            sacc[kc] = __builtin_amdgcn_mfma_f32_16x16x32_bf16(k0, qf[0], sacc[kc], 0, 0, 0);
            sacc[kc] = __builtin_amdgcn_mfma_f32_16x16x32_bf16(k1, qf[1], sacc[kc], 0, 0, 0);
        }

        // ---- p = 2^sacc packed straight into K=32 f16 PV A-fragments ----
        // pk8[c] halves [h*4+r] = exp2(sacc[2c+h][r]); lane k-slice quad*8+i
        // maps to keys c*32 + h*16 + quad*4 + r.
        f16x8 pk8[2];
#pragma unroll
        for (int c = 0; c < 2; c++) {
            union { uint4 u; f16x8 v; } pku;
#pragma unroll
            for (int h = 0; h < 2; h++) {
                float p0 = __builtin_amdgcn_exp2f(sacc[2 * c + h][0]);
                float p1 = __builtin_amdgcn_exp2f(sacc[2 * c + h][1]);
                float p2 = __builtin_amdgcn_exp2f(sacc[2 * c + h][2]);
                float p3 = __builtin_amdgcn_exp2f(sacc[2 * c + h][3]);
                l_r += (p0 + p1) + (p2 + p3);
                union { fp16x2 h2; unsigned int u; } a, b;
                a.h2 = __builtin_amdgcn_cvt_pkrtz(p0, p1);
                b.h2 = __builtin_amdgcn_cvt_pkrtz(p2, p3);
                if (h == 0) { pku.u.x = a.u; pku.u.y = b.u; }
                else        { pku.u.z = a.u; pku.u.w = b.u; }
            }
            pk8[c] = pku.v;
        }

        // ---- O += P V via K=32 f16 mfma; B-frag = concat of two swizzled
        //      f16x4 V^T chunks; half bit XOR (l15>>3) undoes gemm0's
        //      involution AND spreads banks (R13 fix b) ----
        const int hf = (((quad & 1) ^ ((l15 >> 3) & 1))) * 4;
#pragma unroll
        for (int c = 0; c < 2; c++)
#pragma unroll
            for (int dt = 0; dt < 4; dt++) {
                int row = dt * 16 + l15;
                int p0 = (c * 4 +     (quad >> 1)) ^ (l15 & 7);   // keys c*32+quad*4..+3
                int p1 = (c * 4 + 2 + (quad >> 1)) ^ (l15 & 7);   // keys c*32+16+quad*4..+3
                f16x4 v0 = *(const f16x4*)(Vc + row * 64 + p0 * 8 + hf);
                f16x4 v1 = *(const f16x4*)(Vc + row * 64 + p1 * 8 + hf);
                f16x8 vf8 = __builtin_shufflevector(v0, v1, 0, 1, 2, 3, 4, 5, 6, 7);
                oacc[dt] = __builtin_amdgcn_mfma_f32_16x16x32_f16(pk8[c], vf8, oacc[dt], 0, 0, 0);
            }

        __syncthreads();
    }

    // l reduction: sum over quads (keys were split across quad+regs)
    l_r += __shfl_xor(l_r, 16);
    l_r += __shfl_xor(l_r, 32);

    int b = bh >> 4, h = bh & 15;
#pragma unroll
    for (int r = 0; r < 4; r++) {
        float inv = 1.0f / __shfl(l_r, quad * 4 + r);   // lane q4r holds qrow q4r's sum
        int srow = qt * 64 + wid * 16 + quad * 4 + r;
#pragma unroll
        for (int dt = 0; dt < 4; dt++)
            O[((long)(b * S_ + srow)) * 1024 + h * DH_ + dt * 16 + l15] = f2bf(oacc[dt][r] * inv);
    }
}

// ---------------- launch ----------------

extern "C" void kernel_launch(void* const* d_in, const int* in_sizes, int n_in,
                              void* d_out, int out_size, void* d_ws, size_t ws_size,
                              hipStream_t stream)
{
    const float* x  = (const float*)d_in[0];
    const float* Wq = (const float*)d_in[1];
    const float* Wk = (const float*)d_in[2];
    const float* Wv = (const float*)d_in[3];
    const float* Wo = (const float*)d_in[4];
    const float* fw = (const float*)d_in[5];
    float* out = (float*)d_out;

    char* ws = (char*)d_ws;
    unsigned short* xb    = (unsigned short*)(ws);               // 8 MB   [B*S, D] bf16
    unsigned short* WqkvT = (unsigned short*)(ws + 8388608);     // 6 MB   [3072,1024] bf16
    unsigned short* WoT   = (unsigned short*)(ws + 14680064);    // 2 MB   [1024,1024] bf16
    unsigned short* Qb    = (unsigned short*)(ws + 16777216);    // 8 MB   [B,H,S,64] bf16 (pre-scaled Cq)
    unsigned short* Kb    = (unsigned short*)(ws + 25165824);    // 8 MB   [B,H,S,64] bf16 (pre-scaled fw)
    unsigned short* Vt    = (unsigned short*)(ws + 33554432);    // 8 MB   [B,H,64,S] fp16 (half-swapped)
    unsigned short* Ob    = xb;                                  // alias: xb dead after gemm1

    convert_x<<<dim3((B_ * S_ * D_) / 4 / 256), dim3(256), 0, stream>>>(x, xb, B_ * S_ * D_);
    transpose_w<<<dim3(32, 32, 4), dim3(32, 8), 0, stream>>>(
        Wq, Wk, Wv, Wo,
        WqkvT, WqkvT + 1024 * 1024, WqkvT + 2 * 1024 * 1024, WoT);
    gemm128<0><<<dim3(24, 32), dim3(256), 0, stream>>>(xb, WqkvT, Qb, Kb, Vt, (float*)nullptr, fw);
    attn_kernel<<<dim3(S_ / 64, B_ * H_), dim3(256), 0, stream>>>(Qb, Kb, Vt, Ob);
    gemm128<1><<<dim3(8, 32), dim3(256), 0, stream>>>(Ob, WoT,
        (unsigned short*)nullptr, (unsigned short*)nullptr, (unsigned short*)nullptr, out, (const float*)nullptr);
}

// Round 5
// 185.876 us; speedup vs baseline: 1.0938x; 1.0406x over previous
//
#include <hip/hip_runtime.h>
#include <hip/hip_bf16.h>
#include <stdint.h>

#define B_  2
#define S_  2048
#define D_  1024
#define H_  16
#define DH_ 64

typedef __attribute__((ext_vector_type(8))) __bf16    bf16x8;
typedef __attribute__((ext_vector_type(8))) _Float16  f16x8;
typedef __attribute__((ext_vector_type(4))) _Float16  f16x4;
typedef __attribute__((ext_vector_type(2))) __fp16    fp16x2;   // cvt_pkrtz return type
typedef __attribute__((ext_vector_type(4))) float     f32x4;

__device__ inline unsigned short f2bf(float f) {
    union { float f; uint32_t u; } v; v.f = f;
    uint32_t r = (v.u + 0x7fffu + ((v.u >> 16) & 1u)) >> 16;
    return (unsigned short)r;
}

// async global->LDS, 16B per lane. LDS dest = wave-uniform base + lane*16.
__device__ __forceinline__ void g2l16(const unsigned short* g, unsigned short* l) {
    __builtin_amdgcn_global_load_lds(
        (const __attribute__((address_space(1))) unsigned int*)g,
        (__attribute__((address_space(3))) unsigned int*)l,
        16, 0, 0);
}

// ---------------- conversion kernels ----------------

__global__ void convert_x(const float* __restrict__ x, unsigned short* __restrict__ xb, int n) {
    int i = (blockIdx.x * blockDim.x + threadIdx.x) * 4;
    if (i < n) {
        float4 v = *(const float4*)(x + i);
        ushort4 o;
        o.x = f2bf(v.x); o.y = f2bf(v.y); o.z = f2bf(v.z); o.w = f2bf(v.w);
        *(ushort4*)(xb + i) = o;
    }
}

// transpose+convert 1024x1024 fp32 [K][N] -> bf16 [N][K]; z selects matrix
__global__ void transpose_w(const float* __restrict__ s0, const float* __restrict__ s1,
                            const float* __restrict__ s2, const float* __restrict__ s3,
                            unsigned short* __restrict__ d0, unsigned short* __restrict__ d1,
                            unsigned short* __restrict__ d2, unsigned short* __restrict__ d3) {
    __shared__ float tile[32][33];
    const float* src; unsigned short* dst;
    switch (blockIdx.z) {
        case 0: src = s0; dst = d0; break;
        case 1: src = s1; dst = d1; break;
        case 2: src = s2; dst = d2; break;
        default: src = s3; dst = d3; break;
    }
    int n0 = blockIdx.x * 32, k0 = blockIdx.y * 32;
    int tx = threadIdx.x, ty = threadIdx.y;   // (32, 8)
    for (int j = 0; j < 32; j += 8)
        tile[ty + j][tx] = src[(long)(k0 + ty + j) * 1024 + n0 + tx];
    __syncthreads();
    for (int j = 0; j < 32; j += 8)
        dst[(long)(n0 + ty + j) * 1024 + k0 + tx] = f2bf(tile[tx][ty + j]);
}

// ---------------- 128x128 MFMA GEMM, global_load_lds staging ----------------
// MODE 0: scatter epilogue -> Q[B,H,S,64] bf16 (PRE-SCALED by 0.125*log2e),
//         K[B,H,S,64] bf16 (PRE-SCALED by fw[s] - fractal weight folded in),
//         Vt[B,H,64,S] FP16, with per-row half-swap: column s stored at
//         s ^ ((d&8)?4:0). R13: source side of the attn V-read bank fix.
// MODE 1: C fp32 [M,1024] row-major
template<int MODE>
__global__ __launch_bounds__(256, 2)
void gemm128(const unsigned short* __restrict__ A, const unsigned short* __restrict__ Bt,
             unsigned short* __restrict__ Qo, unsigned short* __restrict__ Ko,
             unsigned short* __restrict__ Vt, float* __restrict__ Cout,
             const float* __restrict__ fw)
{
    __shared__ __align__(16) unsigned short As[128 * 64];
    __shared__ __align__(16) unsigned short Bs[128 * 64];
    const int tid  = threadIdx.x;
    const int lane = tid & 63, wid = tid >> 6;
    const int quad = lane >> 4, l15 = lane & 15;
    const int wm = wid >> 1, wn = wid & 1;
    const int bm = blockIdx.y, bn = blockIdx.x;
    const int K = 1024;
    f32x4 acc[4][4] = {};
    const long Abase = (long)bm * 128 * K;
    const long Bbase = (long)bn * 128 * K;

    for (int k0 = 0; k0 < K; k0 += 64) {
        __syncthreads();
#pragma unroll
        for (int i = 0; i < 4; i++) {
            int slot = i * 256 + wid * 64 + lane;
            int row = slot >> 3, cp = slot & 7;
            int c = cp ^ (row & 7);
            g2l16(A + Abase + (long)row * K + k0 + c * 8, &As[(i * 256 + wid * 64) * 8]);
        }
#pragma unroll
        for (int i = 0; i < 4; i++) {
            int slot = i * 256 + wid * 64 + lane;
            int row = slot >> 3, cp = slot & 7;
            int c = cp ^ (row & 7);
            g2l16(Bt + Bbase + (long)row * K + k0 + c * 8, &Bs[(i * 256 + wid * 64) * 8]);
        }
        __syncthreads();
#pragma unroll
        for (int ks = 0; ks < 2; ks++) {
            bf16x8 af[4], bfr[4];
#pragma unroll
            for (int t = 0; t < 4; t++) {
                int ra = wm * 64 + t * 16 + l15;
                af[t]  = *(const bf16x8*)(As + ra * 64 + (((ks * 4 + quad) ^ (l15 & 7))) * 8);
                int rb = wn * 64 + t * 16 + l15;
                bfr[t] = *(const bf16x8*)(Bs + rb * 64 + (((ks * 4 + quad) ^ (l15 & 7))) * 8);
            }
#pragma unroll
            for (int tm = 0; tm < 4; tm++)
#pragma unroll
                for (int tn = 0; tn < 4; tn++)
                    acc[tm][tn] = __builtin_amdgcn_mfma_f32_16x16x32_bf16(af[tm], bfr[tn], acc[tm][tn], 0, 0, 0);
        }
    }

    const float Cq = 0.125f * 1.44269504f;   // score scale * log2(e), folded into Q
    for (int tm = 0; tm < 4; tm++)
        for (int tn = 0; tn < 4; tn++)
            for (int r = 0; r < 4; r++) {
                int gm = bm * 128 + wm * 64 + tm * 16 + quad * 4 + r;
                int gn = bn * 128 + wn * 64 + tn * 16 + l15;
                float v = acc[tm][tn][r];
                if (MODE == 0) {
                    int b = gm >> 11, s = gm & 2047;
                    if (gn < 1024) {
                        int h = gn >> 6, d = gn & 63;
                        Qo[(((long)(b * H_ + h) * S_ + s) << 6) + d] = f2bf(v * Cq);
                    } else if (gn < 2048) {
                        int g = gn - 1024; int h = g >> 6, d = g & 63;
                        Ko[(((long)(b * H_ + h) * S_ + s) << 6) + d] = f2bf(v * fw[s]);
                    } else {
                        int g = gn - 2048; int h = g >> 6, d = g & 63;
                        union { _Float16 h; unsigned short u; } cv;
                        cv.h = (_Float16)v;                       // V^T stored FP16
                        int sp = s ^ ((d & 8) ? 4 : 0);           // R13 half-swap involution
                        Vt[((long)(b * H_ + h) * DH_ + d) * S_ + sp] = cv.u;
                    }
                } else {
                    Cout[(long)gm * 1024 + gn] = v;
                }
            }
}

// ---------------- flash attention: in-block split-K ----------------
// R14 post-mortem chain: R12 (32 qrows/wave) = 8 waves/CU, latency-bound 57us.
// R13 (16 qrows/wave) = 16 waves/CU but LDS traffic/CU doubled -> LDS-BW wall
// (est 41us of 58us = 71% busy), 58us. Caught between two regimes.
// R14: split-K. Softmax is MAX-FREE (pure exp2, fw sums to 1) => partial
// (O, l) over key halves are DIRECTLY ADDABLE - no rescale. Block = 512 thr
// = 8 waves: waves 0-3 do keys [0,1024), waves 4-7 keys [1024,2048), each
// wave back at 32 q-rows (2 strips SHARING K/V fragments = R12's per-work
// LDS traffic, half of R13's). 16 waves/CU AND LDS ~20us/CU. Each half has
// its own double-buffered K/V LDS (64KB/block, 2 blocks/CU = 128KB).
// Combine: post-loop, upper half writes fp32 partial O (+l) into the dead
// K/V LDS, one barrier, lower half adds+normalizes+stores. ~0.3us, no HBM.
// l via MFMA (R14b): 24 fadds+shfls replaced by mfma(pk8, ones) -> lacc[r]
// IS q-row (quad*4+r)'s sum, replicated across l15 -> no shfl at epilogue.
// Register-P (R8), PV K=32 f16 with key-permutation packing (R10),
// V half-swap bank fix (R13b, conflicts 4.19M -> 0) all retained.
__global__ __launch_bounds__(512, 4)
void attn_kernel(const unsigned short* __restrict__ Q, const unsigned short* __restrict__ Kb,
                 const unsigned short* __restrict__ Vt,
                 unsigned short* __restrict__ O)
{
    // [half][buf][K=0/V=1][64*64 shorts] = 64 KB
    __shared__ __align__(16) unsigned short smem[2][2][2][64 * 64];

    const int tid  = threadIdx.x;
    const int lane = tid & 63, wid = tid >> 6;    // wid in {0..7}
    const int half = wid >> 2, sw = wid & 3;      // key-half, sub-wave
    const int quad = lane >> 4, l15 = lane & 15;
    const int bh = blockIdx.y;
    const int qt = blockIdx.x;                    // 128 q-rows per block, 32 per wave

    const unsigned short* Kg = Kb + (long)bh * S_ * DH_;
    const unsigned short* Vg = Vt + (long)bh * (long)DH_ * S_;

    bf16x8 qf[2][2];
#pragma unroll
    for (int st = 0; st < 2; st++) {
        const unsigned short* Qp = Q + ((long)bh * S_ + qt * 128 + sw * 32 + st * 16 + l15) * DH_ + quad * 8;
        qf[st][0] = *(const bf16x8*)(Qp);
        qf[st][1] = *(const bf16x8*)(Qp + 32);
    }

    // stage absolute tile kt into this half's buffer: 512 chunks K + 512 V,
    // 4 sub-waves x 2 rounds each
    auto issue = [&](int buf, int kt) {
#pragma unroll
        for (int i = 0; i < 2; i++) {
            int base = i * 256 + sw * 64;
            int slot = base + lane;
            int row = slot >> 3, cp = slot & 7;
            int c = cp ^ (row & 7);
            g2l16(Kg + ((long)(kt * 64 + row) * 64 + c * 8), &smem[half][buf][0][base * 8]);
        }
#pragma unroll
        for (int i = 0; i < 2; i++) {
            int base = i * 256 + sw * 64;
            int slot = base + lane;
            int row = slot >> 3, cp = slot & 7;
            int c = cp ^ (row & 7);
            g2l16(Vg + ((long)row * S_ + kt * 64 + c * 8), &smem[half][buf][1][base * 8]);
        }
    };

    f32x4 oacc[2][4] = {};
    f32x4 lacc[2] = {};
    const f16x8 vone = {(_Float16)1.f, (_Float16)1.f, (_Float16)1.f, (_Float16)1.f,
                        (_Float16)1.f, (_Float16)1.f, (_Float16)1.f, (_Float16)1.f};

    const int kt0 = half * 16;                    // 16 tiles per half
    issue(0, kt0);
    __syncthreads();

    for (int t = 0; t < 16; t++) {
        const int cur = t & 1;
        if (t + 1 < 16) issue(1 - cur, kt0 + t + 1);

        const unsigned short* Kc = &smem[half][cur][0][0];
        const unsigned short* Vc = &smem[half][cur][1][0];

        // ---- S^T tiles: mfma(K_frag, Q_frag) -> [key=quad*4+r][q=l15] ----
        f32x4 sacc[2][4] = {};
#pragma unroll
        for (int kc = 0; kc < 4; kc++) {
            int row = kc * 16 + l15;
            bf16x8 k0 = *(const bf16x8*)(Kc + (row * 8 + (quad       ^ (l15 & 7))) * 8);
            bf16x8 k1 = *(const bf16x8*)(Kc + (row * 8 + ((4 + quad) ^ (l15 & 7))) * 8);
#pragma unroll
            for (int st = 0; st < 2; st++) {
                sacc[st][kc] = __builtin_amdgcn_mfma_f32_16x16x32_bf16(k0, qf[st][0], sacc[st][kc], 0, 0, 0);
                sacc[st][kc] = __builtin_amdgcn_mfma_f32_16x16x32_bf16(k1, qf[st][1], sacc[st][kc], 0, 0, 0);
            }
        }

        // ---- p = 2^sacc packed into K=32 f16 PV A-fragments (R10 bijection) ----
        f16x8 pk8[2][2];
#pragma unroll
        for (int st = 0; st < 2; st++)
#pragma unroll
            for (int c = 0; c < 2; c++) {
                union { uint4 u; f16x8 v; } pku;
#pragma unroll
                for (int hh = 0; hh < 2; hh++) {
                    float p0 = __builtin_amdgcn_exp2f(sacc[st][2 * c + hh][0]);
                    float p1 = __builtin_amdgcn_exp2f(sacc[st][2 * c + hh][1]);
                    float p2 = __builtin_amdgcn_exp2f(sacc[st][2 * c + hh][2]);
                    float p3 = __builtin_amdgcn_exp2f(sacc[st][2 * c + hh][3]);
                    union { fp16x2 h2; unsigned int u; } a, b;
                    a.h2 = __builtin_amdgcn_cvt_pkrtz(p0, p1);
                    b.h2 = __builtin_amdgcn_cvt_pkrtz(p2, p3);
                    if (hh == 0) { pku.u.x = a.u; pku.u.y = b.u; }
                    else         { pku.u.z = a.u; pku.u.w = b.u; }
                }
                pk8[st][c] = pku.v;
            }

        // ---- O += P V (K=32 f16); l += P ยท 1 via MFMA (R14b);
        //      V half-bit XOR (l15>>3) undoes gemm0 involution + spreads banks ----
        const int hf = (((quad & 1) ^ ((l15 >> 3) & 1))) * 4;
#pragma unroll
        for (int c = 0; c < 2; c++) {
            lacc[0] = __builtin_amdgcn_mfma_f32_16x16x32_f16(pk8[0][c], vone, lacc[0], 0, 0, 0);
            lacc[1] = __builtin_amdgcn_mfma_f32_16x16x32_f16(pk8[1][c], vone, lacc[1], 0, 0, 0);
#pragma unroll
            for (int dt = 0; dt < 4; dt++) {
                int row = dt * 16 + l15;
                int p0 = (c * 4 +     (quad >> 1)) ^ (l15 & 7);
                int p1 = (c * 4 + 2 + (quad >> 1)) ^ (l15 & 7);
                f16x4 v0 = *(const f16x4*)(Vc + row * 64 + p0 * 8 + hf);
                f16x4 v1 = *(const f16x4*)(Vc + row * 64 + p1 * 8 + hf);
                f16x8 vf8 = __builtin_shufflevector(v0, v1, 0, 1, 2, 3, 4, 5, 6, 7);
                oacc[0][dt] = __builtin_amdgcn_mfma_f32_16x16x32_f16(pk8[0][c], vf8, oacc[0][dt], 0, 0, 0);
                oacc[1][dt] = __builtin_amdgcn_mfma_f32_16x16x32_f16(pk8[1][c], vf8, oacc[1][dt], 0, 0, 0);
            }
        }

        __syncthreads();
    }
    // loop ends with a full barrier: all LDS K/V reads complete -> overlay safe

    // combine overlay over the dead K/V LDS: 128 x stride-66 fp32 O + 128 fp32 l
    float* ov = (float*)&smem[0][0][0][0];
    float* lv = ov + 128 * 66;

    if (half == 1) {
#pragma unroll
        for (int st = 0; st < 2; st++) {
#pragma unroll
            for (int dt = 0; dt < 4; dt++)
#pragma unroll
                for (int r = 0; r < 4; r++) {
                    int qr = sw * 32 + st * 16 + quad * 4 + r;
                    ov[qr * 66 + dt * 16 + l15] = oacc[st][dt][r];
                }
            if (l15 == 0) {
#pragma unroll
                for (int r = 0; r < 4; r++)
                    lv[sw * 32 + st * 16 + quad * 4 + r] = lacc[st][r];
            }
        }
    }
    __syncthreads();

    if (half == 0) {
        int b = bh >> 4, h = bh & 15;
#pragma unroll
        for (int st = 0; st < 2; st++)
#pragma unroll
            for (int r = 0; r < 4; r++) {
                int qr = sw * 32 + st * 16 + quad * 4 + r;
                float inv = 1.0f / (lacc[st][r] + lv[qr]);
                int srow = qt * 128 + qr;
#pragma unroll
                for (int dt = 0; dt < 4; dt++) {
                    float val = oacc[st][dt][r] + ov[qr * 66 + dt * 16 + l15];
                    O[((long)(b * S_ + srow)) * 1024 + h * DH_ + dt * 16 + l15] = f2bf(val * inv);
                }
            }
    }
}

// ---------------- launch ----------------

extern "C" void kernel_launch(void* const* d_in, const int* in_sizes, int n_in,
                              void* d_out, int out_size, void* d_ws, size_t ws_size,
                              hipStream_t stream)
{
    const float* x  = (const float*)d_in[0];
    const float* Wq = (const float*)d_in[1];
    const float* Wk = (const float*)d_in[2];
    const float* Wv = (const float*)d_in[3];
    const float* Wo = (const float*)d_in[4];
    const float* fw = (const float*)d_in[5];
    float* out = (float*)d_out;

    char* ws = (char*)d_ws;
    unsigned short* xb    = (unsigned short*)(ws);               // 8 MB   [B*S, D] bf16
    unsigned short* WqkvT = (unsigned short*)(ws + 8388608);     // 6 MB   [3072,1024] bf16
    unsigned short* WoT   = (unsigned short*)(ws + 14680064);    // 2 MB   [1024,1024] bf16
    unsigned short* Qb    = (unsigned short*)(ws + 16777216);    // 8 MB   [B,H,S,64] bf16 (pre-scaled Cq)
    unsigned short* Kb    = (unsigned short*)(ws + 25165824);    // 8 MB   [B,H,S,64] bf16 (pre-scaled fw)
    unsigned short* Vt    = (unsigned short*)(ws + 33554432);    // 8 MB   [B,H,64,S] fp16 (half-swapped)
    unsigned short* Ob    = xb;                                  // alias: xb dead after gemm1

    convert_x<<<dim3((B_ * S_ * D_) / 4 / 256), dim3(256), 0, stream>>>(x, xb, B_ * S_ * D_);
    transpose_w<<<dim3(32, 32, 4), dim3(32, 8), 0, stream>>>(
        Wq, Wk, Wv, Wo,
        WqkvT, WqkvT + 1024 * 1024, WqkvT + 2 * 1024 * 1024, WoT);
    gemm128<0><<<dim3(24, 32), dim3(256), 0, stream>>>(xb, WqkvT, Qb, Kb, Vt, (float*)nullptr, fw);
    attn_kernel<<<dim3(S_ / 128, B_ * H_), dim3(512), 0, stream>>>(Qb, Kb, Vt, Ob);
    gemm128<1><<<dim3(8, 32), dim3(256), 0, stream>>>(Ob, WoT,
        (unsigned short*)nullptr, (unsigned short*)nullptr, (unsigned short*)nullptr, out, (const float*)nullptr);
}